// Round 2
// baseline (507.651 us; speedup 1.0000x reference)
//
#include <hip/hip_runtime.h>

#define N_NODES 100000
#define N_EDGES 300000
#define N_GRAPHS 4000
#define CAP 32

// ---------------- workspace layout (float offsets) ----------------
// total ~83 MB (fits comfortably in a 128 MB workspace)
static const size_t OFF_ASAD1 = 0;                                  // N*8
static const size_t OFF_WF    = OFF_ASAD1 + (size_t)N_NODES * 8;    // 128
static const size_t OFF_AGGN  = OFF_WF + 128;                       // N*36
static const size_t OFF_P2    = OFF_AGGN + (size_t)N_NODES * 36;    // N*128
static const size_t OFF_ASAD2 = OFF_P2 + (size_t)N_NODES * 128;     // N*2
static const size_t OFF_INT   = OFF_ASAD2 + (size_t)N_NODES * 2;    // deg[N], bucket[N*CAP], gstart[G+1]

__device__ __forceinline__ float lrelu(float x) { return x < 0.f ? 0.2f * x : x; }
__device__ __forceinline__ float elu(float x)   { return x > 0.f ? x : __expf(x) - 1.f; }

// fold W1 with a_src1/a_dst1 -> wf[isd*36 + k*4 + h]
__global__ void k_fold1(const float* __restrict__ W1, const float* __restrict__ a_src1,
                        const float* __restrict__ a_dst1, float* __restrict__ wf) {
    int o = blockIdx.x;            // 72 blocks
    int c = threadIdx.x;           // 128 threads
    int isd = o / 36, r = o % 36, k = r / 4, h = r % 4;
    const float* a = isd ? a_dst1 : a_src1;
    float v = W1[k * 512 + h * 128 + c] * a[h * 128 + c];
    __shared__ float red[128];
    red[c] = v;
    __syncthreads();
    for (int s = 64; s > 0; s >>= 1) {
        if (c < s) red[c] += red[c + s];
        __syncthreads();
    }
    if (c == 0) wf[isd * 36 + k * 4 + h] = red[0];
}

// per-node attention scalars for layer 1
__global__ void k_asad1(const float* __restrict__ x, const float* __restrict__ wf,
                        float* __restrict__ asad1) {
    int n = blockIdx.x * 256 + threadIdx.x;
    if (n >= N_NODES) return;
    float xv[9];
#pragma unroll
    for (int k = 0; k < 9; k++) xv[k] = x[n * 9 + k];
#pragma unroll
    for (int h = 0; h < 4; h++) {
        float s = 0.f, d = 0.f;
#pragma unroll
        for (int k = 0; k < 9; k++) {
            s += xv[k] * wf[k * 4 + h];
            d += xv[k] * wf[36 + k * 4 + h];
        }
        asad1[n * 8 + h] = s;
        asad1[n * 8 + 4 + h] = d;
    }
}

// build per-dst bucket of src ids
__global__ void k_bucket(const int* __restrict__ ei, int* __restrict__ deg,
                         int* __restrict__ bucket) {
    int e = blockIdx.x * 256 + threadIdx.x;
    if (e >= N_EDGES) return;
    int s = ei[e], d = ei[N_EDGES + e];
    int slot = atomicAdd(&deg[d], 1);
    if (slot < CAP) bucket[d * CAP + slot] = s;
}

// layer-1 attention + aggregation of x (normalized)
__global__ void k_agg1(const float* __restrict__ x, const float* __restrict__ asad1,
                       const int* __restrict__ deg, const int* __restrict__ bucket,
                       float* __restrict__ aggN) {
    int n = blockIdx.x * 256 + threadIdx.x;
    if (n >= N_NODES) return;
    float4 adv = *(const float4*)(asad1 + n * 8 + 4);
    float ad[4] = {adv.x, adv.y, adv.z, adv.w};
    float4 asv = *(const float4*)(asad1 + n * 8);
    float asl[4] = {asv.x, asv.y, asv.z, asv.w};
    float xs[9];
#pragma unroll
    for (int k = 0; k < 9; k++) xs[k] = x[n * 9 + k];
    float acc[4][9], z[4];
#pragma unroll
    for (int h = 0; h < 4; h++) {
        float e = __expf(lrelu(asl[h] + ad[h]));  // self loop
        z[h] = e;
#pragma unroll
        for (int k = 0; k < 9; k++) acc[h][k] = e * xs[k];
    }
    int dg = deg[n];
    if (dg > CAP) dg = CAP;
    for (int j = 0; j < dg; j++) {
        int s = bucket[n * CAP + j];
        float4 av = *(const float4*)(asad1 + s * 8);
        float as_[4] = {av.x, av.y, av.z, av.w};
        float xv[9];
#pragma unroll
        for (int k = 0; k < 9; k++) xv[k] = x[s * 9 + k];
#pragma unroll
        for (int h = 0; h < 4; h++) {
            float e = __expf(lrelu(as_[h] + ad[h]));
            z[h] += e;
#pragma unroll
            for (int k = 0; k < 9; k++) acc[h][k] += e * xv[k];
        }
    }
#pragma unroll
    for (int h = 0; h < 4; h++) {
        float inv = 1.f / z[h];
#pragma unroll
        for (int k = 0; k < 9; k++) aggN[n * 36 + h * 9 + k] = acc[h][k] * inv;
    }
}

// fused: h2-tile = elu(aggN@W1 + b1) computed on the fly; p2 = h2 @ W2
// 64x64 tile, 4x4 per thread, fp32
__global__ __launch_bounds__(256) void k_gemm_fused(const float* __restrict__ aggN,
                                                    const float* __restrict__ W1,
                                                    const float* __restrict__ b1,
                                                    const float* __restrict__ W2,
                                                    float* __restrict__ C) {
    __shared__ float Ag[64 * 36];  // aggN tile
    __shared__ float As[64 * 36];  // h2 tile [m][krel], row len 36 (32 used + pad)
    __shared__ float Bs[32 * 68];  // W2 tile [k][n], row len 68
    int tid = threadIdx.x;
    int tx = tid & 15, ty = tid >> 4;
    int m0 = blockIdx.x * 64, n0 = blockIdx.y * 64;
    for (int i = tid; i < 64 * 36; i += 256) {
        int m = i / 36, k = i % 36;
        int row = m0 + m;
        Ag[i] = (row < N_NODES) ? aggN[(size_t)row * 36 + k] : 0.f;
    }
    __syncthreads();
    float acc[4][4] = {};
    for (int kc = 0; kc < 512; kc += 32) {
        // compute h2 tile (elu(aggN@W1 + b1)) for columns [kc, kc+32)
#pragma unroll
        for (int i = 0; i < 8; i++) {
            int e = tid + i * 256;
            int m = e >> 5, krel = e & 31;
            int j = kc + krel;           // h2 column
            int h = j >> 7;              // head
            const float* ag = &Ag[m * 36 + h * 9];
            float a = b1[j];
#pragma unroll
            for (int k = 0; k < 9; k++) a += ag[k] * W1[k * 512 + j];
            As[m * 36 + krel] = elu(a);
        }
#pragma unroll
        for (int i = 0; i < 8; i++) {
            int e = tid + i * 256;
            int nn = e & 63, krel = e >> 6;
            Bs[krel * 68 + nn] = W2[(kc + krel) * 128 + n0 + nn];
        }
        __syncthreads();
#pragma unroll
        for (int k4 = 0; k4 < 8; k4++) {
            float4 a[4], b[4];
#pragma unroll
            for (int r = 0; r < 4; r++)
                a[r] = *(const float4*)&As[(ty * 4 + r) * 36 + k4 * 4];
#pragma unroll
            for (int kk = 0; kk < 4; kk++)
                b[kk] = *(const float4*)&Bs[(k4 * 4 + kk) * 68 + tx * 4];
#pragma unroll
            for (int r = 0; r < 4; r++) {
                acc[r][0] += a[r].x * b[0].x; acc[r][1] += a[r].x * b[0].y;
                acc[r][2] += a[r].x * b[0].z; acc[r][3] += a[r].x * b[0].w;
                acc[r][0] += a[r].y * b[1].x; acc[r][1] += a[r].y * b[1].y;
                acc[r][2] += a[r].y * b[1].z; acc[r][3] += a[r].y * b[1].w;
                acc[r][0] += a[r].z * b[2].x; acc[r][1] += a[r].z * b[2].y;
                acc[r][2] += a[r].z * b[2].z; acc[r][3] += a[r].z * b[2].w;
                acc[r][0] += a[r].w * b[3].x; acc[r][1] += a[r].w * b[3].y;
                acc[r][2] += a[r].w * b[3].z; acc[r][3] += a[r].w * b[3].w;
            }
        }
        __syncthreads();
    }
#pragma unroll
    for (int r = 0; r < 4; r++) {
        int row = m0 + ty * 4 + r;
        if (row < N_NODES) {
            float4 v = {acc[r][0], acc[r][1], acc[r][2], acc[r][3]};
            *(float4*)&C[(size_t)row * 128 + n0 + tx * 4] = v;
        }
    }
}

// layer-2 attention scalars from p2
__global__ void k_asad2(const float* __restrict__ p2, const float* __restrict__ a_src2,
                        const float* __restrict__ a_dst2, float* __restrict__ asad2) {
    int wid = (blockIdx.x * 256 + threadIdx.x) >> 6;
    int lane = threadIdx.x & 63;
    if (wid >= N_NODES) return;
    float v0 = p2[(size_t)wid * 128 + lane], v1 = p2[(size_t)wid * 128 + 64 + lane];
    float s = v0 * a_src2[lane] + v1 * a_src2[64 + lane];
    float d = v0 * a_dst2[lane] + v1 * a_dst2[64 + lane];
    for (int off = 32; off > 0; off >>= 1) {
        s += __shfl_down(s, off, 64);
        d += __shfl_down(d, off, 64);
    }
    if (lane == 0) {
        asad2[wid * 2] = s;
        asad2[wid * 2 + 1] = d;
    }
}

// layer-2 attention + aggregation + elu + fused graph-sum (atomics into out)
__global__ void k_agg2_pool(const float* __restrict__ p2, const float* __restrict__ asad2,
                            const int* __restrict__ deg, const int* __restrict__ bucket,
                            const float* __restrict__ b2, const int* __restrict__ batch,
                            float* __restrict__ out) {
    int wid = (blockIdx.x * 256 + threadIdx.x) >> 6;
    int lane = threadIdx.x & 63;
    if (wid >= N_NODES) return;
    int n = wid;
    float ad = asad2[n * 2 + 1];
    float e = __expf(lrelu(asad2[n * 2] + ad));  // self loop
    float z = e;
    float a0 = e * p2[(size_t)n * 128 + lane];
    float a1 = e * p2[(size_t)n * 128 + 64 + lane];
    int dg = deg[n];
    if (dg > CAP) dg = CAP;
    for (int j = 0; j < dg; j++) {
        int s = bucket[n * CAP + j];
        float e2 = __expf(lrelu(asad2[s * 2] + ad));
        z += e2;
        a0 += e2 * p2[(size_t)s * 128 + lane];
        a1 += e2 * p2[(size_t)s * 128 + 64 + lane];
    }
    float inv = 1.f / z;
    int g = batch[n];
    atomicAdd(&out[(size_t)g * 128 + lane], elu(a0 * inv + b2[lane]));
    atomicAdd(&out[(size_t)g * 128 + 64 + lane], elu(a1 * inv + b2[64 + lane]));
}

// graph start offsets via binary search (batch is sorted)
__global__ void k_gstart(const int* __restrict__ batch, int* __restrict__ gstart) {
    int g = blockIdx.x * 256 + threadIdx.x;
    if (g > N_GRAPHS) return;
    int lo = 0, hi = N_NODES;
    while (lo < hi) {
        int mid = (lo + hi) >> 1;
        if (batch[mid] < g) lo = mid + 1; else hi = mid;
    }
    gstart[g] = lo;
}

// divide pooled sums by per-graph node counts
__global__ void k_div(const int* __restrict__ gstart, float* __restrict__ out) {
    int g = blockIdx.x, j = threadIdx.x;
    int c = gstart[g + 1] - gstart[g];
    out[(size_t)g * 128 + j] /= (float)(c > 0 ? c : 1);
}

extern "C" void kernel_launch(void* const* d_in, const int* in_sizes, int n_in,
                              void* d_out, int out_size, void* d_ws, size_t ws_size,
                              hipStream_t stream) {
    const float* x       = (const float*)d_in[0];
    const int*   ei      = (const int*)d_in[1];
    const int*   batch   = (const int*)d_in[2];
    const float* W1      = (const float*)d_in[3];
    const float* a_src1  = (const float*)d_in[4];
    const float* a_dst1  = (const float*)d_in[5];
    const float* b1      = (const float*)d_in[6];
    const float* W2      = (const float*)d_in[7];
    const float* a_src2  = (const float*)d_in[8];
    const float* a_dst2  = (const float*)d_in[9];
    const float* b2      = (const float*)d_in[10];
    float* out = (float*)d_out;

    float* wsf   = (float*)d_ws;
    float* asad1 = wsf + OFF_ASAD1;
    float* wf    = wsf + OFF_WF;
    float* aggN  = wsf + OFF_AGGN;
    float* p2    = wsf + OFF_P2;
    float* asad2 = wsf + OFF_ASAD2;
    int* wsi    = (int*)(wsf + OFF_INT);
    int* deg    = wsi;
    int* bucket = wsi + N_NODES;
    int* gstart = wsi + N_NODES + (size_t)N_NODES * CAP;

    hipMemsetAsync(deg, 0, N_NODES * sizeof(int), stream);
    hipMemsetAsync(out, 0, (size_t)out_size * sizeof(float), stream);

    k_fold1<<<72, 128, 0, stream>>>(W1, a_src1, a_dst1, wf);
    k_asad1<<<(N_NODES + 255) / 256, 256, 0, stream>>>(x, wf, asad1);
    k_bucket<<<(N_EDGES + 255) / 256, 256, 0, stream>>>(ei, deg, bucket);
    k_agg1<<<(N_NODES + 255) / 256, 256, 0, stream>>>(x, asad1, deg, bucket, aggN);
    k_gemm_fused<<<dim3((N_NODES + 63) / 64, 2), 256, 0, stream>>>(aggN, W1, b1, W2, p2);
    k_asad2<<<(N_NODES * 64) / 256, 256, 0, stream>>>(p2, a_src2, a_dst2, asad2);
    k_gstart<<<(N_GRAPHS + 256) / 256, 256, 0, stream>>>(batch, gstart);
    k_agg2_pool<<<(N_NODES * 64) / 256, 256, 0, stream>>>(p2, asad2, deg, bucket, b2, batch, out);
    k_div<<<N_GRAPHS, 128, 0, stream>>>(gstart, out);
}

// Round 3
// 279.263 us; speedup vs baseline: 1.8178x; 1.8178x over previous
//
#include <hip/hip_runtime.h>

#define N_NODES 100000
#define N_EDGES 300000
#define N_GRAPHS 4000
#define CAP 32

typedef float f32x4 __attribute__((ext_vector_type(4)));
typedef __bf16 bf16x4 __attribute__((ext_vector_type(4)));
typedef __bf16 bf16x8 __attribute__((ext_vector_type(8)));

// ---------------- workspace layout (float offsets) ----------------
static const size_t OFF_ASAD1 = 0;                                  // N*8
static const size_t OFF_WF    = OFF_ASAD1 + (size_t)N_NODES * 8;    // 128
static const size_t OFF_AGGN  = OFF_WF + 128;                       // N*36
static const size_t OFF_P2    = OFF_AGGN + (size_t)N_NODES * 36;    // N*128
static const size_t OFF_ASAD2 = OFF_P2 + (size_t)N_NODES * 128;     // N*2
static const size_t OFF_WSB   = OFF_ASAD2 + (size_t)N_NODES * 2;    // 32768 floats = 65536 bf16
static const size_t OFF_INT   = OFF_WSB + 32768;                    // deg[N], bucket[N*CAP], gstart[G+1]

__device__ __forceinline__ float lrelu(float x) { return x < 0.f ? 0.2f * x : x; }
__device__ __forceinline__ float elu(float x)   { return x > 0.f ? x : __expf(x) - 1.f; }

// fold W1 with a_src1/a_dst1 -> wf[isd*36 + k*4 + h]
__global__ void k_fold1(const float* __restrict__ W1, const float* __restrict__ a_src1,
                        const float* __restrict__ a_dst1, float* __restrict__ wf) {
    int o = blockIdx.x;            // 72 blocks
    int c = threadIdx.x;           // 128 threads
    int isd = o / 36, r = o % 36, k = r / 4, h = r % 4;
    const float* a = isd ? a_dst1 : a_src1;
    float v = W1[k * 512 + h * 128 + c] * a[h * 128 + c];
    __shared__ float red[128];
    red[c] = v;
    __syncthreads();
    for (int s = 64; s > 0; s >>= 1) {
        if (c < s) red[c] += red[c + s];
        __syncthreads();
    }
    if (c == 0) wf[isd * 36 + k * 4 + h] = red[0];
}

// per-node attention scalars for layer 1
__global__ void k_asad1(const float* __restrict__ x, const float* __restrict__ wf,
                        float* __restrict__ asad1) {
    int n = blockIdx.x * 256 + threadIdx.x;
    if (n >= N_NODES) return;
    float xv[9];
#pragma unroll
    for (int k = 0; k < 9; k++) xv[k] = x[n * 9 + k];
#pragma unroll
    for (int h = 0; h < 4; h++) {
        float s = 0.f, d = 0.f;
#pragma unroll
        for (int k = 0; k < 9; k++) {
            s += xv[k] * wf[k * 4 + h];
            d += xv[k] * wf[36 + k * 4 + h];
        }
        asad1[n * 8 + h] = s;
        asad1[n * 8 + 4 + h] = d;
    }
}

// build per-dst bucket of src ids
__global__ void k_bucket(const int* __restrict__ ei, int* __restrict__ deg,
                         int* __restrict__ bucket) {
    int e = blockIdx.x * 256 + threadIdx.x;
    if (e >= N_EDGES) return;
    int s = ei[e], d = ei[N_EDGES + e];
    int slot = atomicAdd(&deg[d], 1);
    if (slot < CAP) bucket[d * CAP + slot] = s;
}

// layer-1 attention + aggregation of x (normalized)
__global__ void k_agg1(const float* __restrict__ x, const float* __restrict__ asad1,
                       const int* __restrict__ deg, const int* __restrict__ bucket,
                       float* __restrict__ aggN) {
    int n = blockIdx.x * 256 + threadIdx.x;
    if (n >= N_NODES) return;
    float4 adv = *(const float4*)(asad1 + n * 8 + 4);
    float ad[4] = {adv.x, adv.y, adv.z, adv.w};
    float4 asv = *(const float4*)(asad1 + n * 8);
    float asl[4] = {asv.x, asv.y, asv.z, asv.w};
    float xs[9];
#pragma unroll
    for (int k = 0; k < 9; k++) xs[k] = x[n * 9 + k];
    float acc[4][9], z[4];
#pragma unroll
    for (int h = 0; h < 4; h++) {
        float e = __expf(lrelu(asl[h] + ad[h]));  // self loop
        z[h] = e;
#pragma unroll
        for (int k = 0; k < 9; k++) acc[h][k] = e * xs[k];
    }
    int dg = deg[n];
    if (dg > CAP) dg = CAP;
    for (int j = 0; j < dg; j++) {
        int s = bucket[n * CAP + j];
        float4 av = *(const float4*)(asad1 + s * 8);
        float as_[4] = {av.x, av.y, av.z, av.w};
        float xv[9];
#pragma unroll
        for (int k = 0; k < 9; k++) xv[k] = x[s * 9 + k];
#pragma unroll
        for (int h = 0; h < 4; h++) {
            float e = __expf(lrelu(as_[h] + ad[h]));
            z[h] += e;
#pragma unroll
            for (int k = 0; k < 9; k++) acc[h][k] += e * xv[k];
        }
    }
#pragma unroll
    for (int h = 0; h < 4; h++) {
        float inv = 1.f / z[h];
#pragma unroll
        for (int k = 0; k < 9; k++) aggN[n * 36 + h * 9 + k] = acc[h][k] * inv;
    }
}

// pre-transpose + bf16-convert W2 [512,128] -> wsB [n=128][k=512]
__global__ void k_packB(const float* __restrict__ W2, __bf16* __restrict__ wsB) {
    int t = blockIdx.x * 256 + threadIdx.x;   // 65536 threads
    int k = t >> 7, n = t & 127;
    wsB[(size_t)n * 512 + k] = (__bf16)W2[(size_t)k * 128 + n];
}

// fused: h2-tile = elu(aggN@W1+b1) -> bf16 LDS; p2 = h2 @ W2 via MFMA;
// epilogue also computes asad2 = p2 . a_src2/a_dst2 (atomics).
// BM=128, BN=128, BK=32; 4 waves 2x2, each wave 64x64 via 4x4 mfma 16x16x32 bf16.
__global__ __launch_bounds__(256) void k_gemm_mfma(
    const float* __restrict__ aggN, const float* __restrict__ W1,
    const float* __restrict__ b1, const __bf16* __restrict__ wsB,
    const float* __restrict__ a_src2, const float* __restrict__ a_dst2,
    float* __restrict__ p2, float* __restrict__ asad2) {
    __shared__ __bf16 As[128 * 40];   // [row][krel], pad 40 -> b128-aligned, low-conflict
    const int tid = threadIdx.x;
    const int m0 = blockIdx.x * 128;
    const int lane = tid & 63;
    const int wid = tid >> 6;
    const int wy = wid >> 1, wx = wid & 1;
    const int quad = lane >> 4, l15 = lane & 15;
    // h2-compute role: 8 col-groups of 4, 32 row-slots x 4 rows
    const int cg = tid & 7;
    const int hr = tid >> 3;

    f32x4 acc[4][4];
#pragma unroll
    for (int r = 0; r < 4; r++)
#pragma unroll
        for (int c = 0; c < 4; c++) acc[r][c] = (f32x4){0.f, 0.f, 0.f, 0.f};

    for (int h = 0; h < 4; h++) {
        float ag[4][9];
#pragma unroll
        for (int r = 0; r < 4; r++) {
            int row = m0 + hr + r * 32;
            if (row < N_NODES) {
#pragma unroll
                for (int k = 0; k < 9; k++) ag[r][k] = aggN[(size_t)row * 36 + h * 9 + k];
            } else {
#pragma unroll
                for (int k = 0; k < 9; k++) ag[r][k] = 0.f;
            }
        }
#pragma unroll
        for (int ki = 0; ki < 4; ki++) {
            const int kc = h * 128 + ki * 32;
            const int j0 = kc + cg * 4;
            f32x4 bv = *(const f32x4*)&b1[j0];
            float o[4][4];
#pragma unroll
            for (int r = 0; r < 4; r++)
#pragma unroll
                for (int c = 0; c < 4; c++) o[r][c] = bv[c];
#pragma unroll
            for (int k = 0; k < 9; k++) {
                f32x4 w = *(const f32x4*)&W1[k * 512 + j0];
#pragma unroll
                for (int r = 0; r < 4; r++) {
                    o[r][0] += ag[r][k] * w.x;
                    o[r][1] += ag[r][k] * w.y;
                    o[r][2] += ag[r][k] * w.z;
                    o[r][3] += ag[r][k] * w.w;
                }
            }
#pragma unroll
            for (int r = 0; r < 4; r++) {
                bf16x4 pk;
#pragma unroll
                for (int c = 0; c < 4; c++) pk[c] = (__bf16)elu(o[r][c]);
                *(bf16x4*)&As[(hr + r * 32) * 40 + cg * 4] = pk;
            }
            __syncthreads();
            // MFMA phase
            bf16x8 bfr[4];
#pragma unroll
            for (int c = 0; c < 4; c++) {
                int col = wx * 64 + c * 16 + l15;
                bfr[c] = *(const bf16x8*)&wsB[(size_t)col * 512 + kc + quad * 8];
            }
#pragma unroll
            for (int r = 0; r < 4; r++) {
                bf16x8 af = *(const bf16x8*)&As[(wy * 64 + r * 16 + l15) * 40 + quad * 8];
#pragma unroll
                for (int c = 0; c < 4; c++)
                    acc[r][c] = __builtin_amdgcn_mfma_f32_16x16x32_bf16(af, bfr[c], acc[r][c], 0, 0, 0);
            }
            __syncthreads();
        }
    }

    // epilogue: store p2 + fused asad2 reduction
    float as2[4], ad2[4];
#pragma unroll
    for (int c = 0; c < 4; c++) {
        int col = wx * 64 + c * 16 + l15;
        as2[c] = a_src2[col];
        ad2[c] = a_dst2[col];
    }
#pragma unroll
    for (int r = 0; r < 4; r++) {
#pragma unroll
        for (int q = 0; q < 4; q++) {
            int row = m0 + wy * 64 + r * 16 + quad * 4 + q;
            float s = 0.f, d = 0.f;
#pragma unroll
            for (int c = 0; c < 4; c++) {
                s += acc[r][c][q] * as2[c];
                d += acc[r][c][q] * ad2[c];
            }
#pragma unroll
            for (int off = 1; off < 16; off <<= 1) {
                s += __shfl_xor(s, off);
                d += __shfl_xor(d, off);
            }
            if (row < N_NODES) {
                if (l15 == 0) {
                    atomicAdd(&asad2[row * 2], s);
                    atomicAdd(&asad2[row * 2 + 1], d);
                }
#pragma unroll
                for (int c = 0; c < 4; c++)
                    p2[(size_t)row * 128 + wx * 64 + c * 16 + l15] = acc[r][c][q];
            }
        }
    }
}

// layer-2 attention + aggregation + elu + fused graph-sum (atomics into out)
__global__ void k_agg2_pool(const float* __restrict__ p2, const float* __restrict__ asad2,
                            const int* __restrict__ deg, const int* __restrict__ bucket,
                            const float* __restrict__ b2, const int* __restrict__ batch,
                            float* __restrict__ out) {
    int wid = (blockIdx.x * 256 + threadIdx.x) >> 6;
    int lane = threadIdx.x & 63;
    if (wid >= N_NODES) return;
    int n = wid;
    float ad = asad2[n * 2 + 1];
    float e = __expf(lrelu(asad2[n * 2] + ad));  // self loop
    float z = e;
    float a0 = e * p2[(size_t)n * 128 + lane];
    float a1 = e * p2[(size_t)n * 128 + 64 + lane];
    int dg = deg[n];
    if (dg > CAP) dg = CAP;
    for (int j = 0; j < dg; j++) {
        int s = bucket[n * CAP + j];
        float e2 = __expf(lrelu(asad2[s * 2] + ad));
        z += e2;
        a0 += e2 * p2[(size_t)s * 128 + lane];
        a1 += e2 * p2[(size_t)s * 128 + 64 + lane];
    }
    float inv = 1.f / z;
    int g = batch[n];
    atomicAdd(&out[(size_t)g * 128 + lane], elu(a0 * inv + b2[lane]));
    atomicAdd(&out[(size_t)g * 128 + 64 + lane], elu(a1 * inv + b2[64 + lane]));
}

// graph start offsets via binary search (batch is sorted)
__global__ void k_gstart(const int* __restrict__ batch, int* __restrict__ gstart) {
    int g = blockIdx.x * 256 + threadIdx.x;
    if (g > N_GRAPHS) return;
    int lo = 0, hi = N_NODES;
    while (lo < hi) {
        int mid = (lo + hi) >> 1;
        if (batch[mid] < g) lo = mid + 1; else hi = mid;
    }
    gstart[g] = lo;
}

// divide pooled sums by per-graph node counts
__global__ void k_div(const int* __restrict__ gstart, float* __restrict__ out) {
    int g = blockIdx.x, j = threadIdx.x;
    int c = gstart[g + 1] - gstart[g];
    out[(size_t)g * 128 + j] /= (float)(c > 0 ? c : 1);
}

extern "C" void kernel_launch(void* const* d_in, const int* in_sizes, int n_in,
                              void* d_out, int out_size, void* d_ws, size_t ws_size,
                              hipStream_t stream) {
    const float* x       = (const float*)d_in[0];
    const int*   ei      = (const int*)d_in[1];
    const int*   batch   = (const int*)d_in[2];
    const float* W1      = (const float*)d_in[3];
    const float* a_src1  = (const float*)d_in[4];
    const float* a_dst1  = (const float*)d_in[5];
    const float* b1      = (const float*)d_in[6];
    const float* W2      = (const float*)d_in[7];
    const float* a_src2  = (const float*)d_in[8];
    const float* a_dst2  = (const float*)d_in[9];
    const float* b2      = (const float*)d_in[10];
    float* out = (float*)d_out;

    float* wsf   = (float*)d_ws;
    float* asad1 = wsf + OFF_ASAD1;
    float* wf    = wsf + OFF_WF;
    float* aggN  = wsf + OFF_AGGN;
    float* p2    = wsf + OFF_P2;
    float* asad2 = wsf + OFF_ASAD2;
    __bf16* wsB  = (__bf16*)(wsf + OFF_WSB);
    int* wsi    = (int*)(wsf + OFF_INT);
    int* deg    = wsi;
    int* bucket = wsi + N_NODES;
    int* gstart = wsi + N_NODES + (size_t)N_NODES * CAP;

    hipMemsetAsync(deg, 0, N_NODES * sizeof(int), stream);
    hipMemsetAsync(asad2, 0, (size_t)N_NODES * 2 * sizeof(float), stream);
    hipMemsetAsync(out, 0, (size_t)out_size * sizeof(float), stream);

    k_fold1<<<72, 128, 0, stream>>>(W1, a_src1, a_dst1, wf);
    k_asad1<<<(N_NODES + 255) / 256, 256, 0, stream>>>(x, wf, asad1);
    k_bucket<<<(N_EDGES + 255) / 256, 256, 0, stream>>>(ei, deg, bucket);
    k_agg1<<<(N_NODES + 255) / 256, 256, 0, stream>>>(x, asad1, deg, bucket, aggN);
    k_packB<<<256, 256, 0, stream>>>(W2, wsB);
    k_gemm_mfma<<<(N_NODES + 127) / 128, 256, 0, stream>>>(aggN, W1, b1, wsB,
                                                           a_src2, a_dst2, p2, asad2);
    k_gstart<<<(N_GRAPHS + 256) / 256, 256, 0, stream>>>(batch, gstart);
    k_agg2_pool<<<(N_NODES * 64) / 256, 256, 0, stream>>>(p2, asad2, deg, bucket, b2, batch, out);
    k_div<<<N_GRAPHS, 128, 0, stream>>>(gstart, out);
}

// Round 4
// 272.823 us; speedup vs baseline: 1.8607x; 1.0236x over previous
//
#include <hip/hip_runtime.h>

#define N_NODES 100000
#define N_EDGES 300000
#define N_GRAPHS 4000
#define CAP 32

typedef float f32x4 __attribute__((ext_vector_type(4)));
typedef __bf16 bf16x8 __attribute__((ext_vector_type(8)));

// ---------------- workspace layout (float offsets) ----------------
static const size_t OFF_ASAD1 = 0;                                  // N*8
static const size_t OFF_WF    = OFF_ASAD1 + (size_t)N_NODES * 8;    // 128
static const size_t OFF_AGGN  = OFF_WF + 128;                       // N*36
static const size_t OFF_P2    = OFF_AGGN + (size_t)N_NODES * 36;    // N*128
static const size_t OFF_ASAD2 = OFF_P2 + (size_t)N_NODES * 128;     // N*2
static const size_t OFF_WSB   = OFF_ASAD2 + (size_t)N_NODES * 2;    // 32768 floats = 65536 bf16
static const size_t OFF_INT   = OFF_WSB + 32768;                    // deg[N], bucket[N*CAP], gstart[G+1]

__device__ __forceinline__ float lrelu(float x) { return x < 0.f ? 0.2f * x : x; }
__device__ __forceinline__ float elu(float x)   { return x > 0.f ? x : __expf(x) - 1.f; }

// fold W1 with a_src1/a_dst1 -> wf[isd*36 + k*4 + h]
__global__ void k_fold1(const float* __restrict__ W1, const float* __restrict__ a_src1,
                        const float* __restrict__ a_dst1, float* __restrict__ wf) {
    int o = blockIdx.x;            // 72 blocks
    int c = threadIdx.x;           // 128 threads
    int isd = o / 36, r = o % 36, k = r / 4, h = r % 4;
    const float* a = isd ? a_dst1 : a_src1;
    float v = W1[k * 512 + h * 128 + c] * a[h * 128 + c];
    __shared__ float red[128];
    red[c] = v;
    __syncthreads();
    for (int s = 64; s > 0; s >>= 1) {
        if (c < s) red[c] += red[c + s];
        __syncthreads();
    }
    if (c == 0) wf[isd * 36 + k * 4 + h] = red[0];
}

// per-node attention scalars for layer 1
__global__ void k_asad1(const float* __restrict__ x, const float* __restrict__ wf,
                        float* __restrict__ asad1) {
    int n = blockIdx.x * 256 + threadIdx.x;
    if (n >= N_NODES) return;
    float xv[9];
#pragma unroll
    for (int k = 0; k < 9; k++) xv[k] = x[n * 9 + k];
#pragma unroll
    for (int h = 0; h < 4; h++) {
        float s = 0.f, d = 0.f;
#pragma unroll
        for (int k = 0; k < 9; k++) {
            s += xv[k] * wf[k * 4 + h];
            d += xv[k] * wf[36 + k * 4 + h];
        }
        asad1[n * 8 + h] = s;
        asad1[n * 8 + 4 + h] = d;
    }
}

// build per-dst bucket of src ids
__global__ void k_bucket(const int* __restrict__ ei, int* __restrict__ deg,
                         int* __restrict__ bucket) {
    int e = blockIdx.x * 256 + threadIdx.x;
    if (e >= N_EDGES) return;
    int s = ei[e], d = ei[N_EDGES + e];
    int slot = atomicAdd(&deg[d], 1);
    if (slot < CAP) bucket[d * CAP + slot] = s;
}

// layer-1 attention + aggregation of x (normalized)
__global__ void k_agg1(const float* __restrict__ x, const float* __restrict__ asad1,
                       const int* __restrict__ deg, const int* __restrict__ bucket,
                       float* __restrict__ aggN) {
    int n = blockIdx.x * 256 + threadIdx.x;
    if (n >= N_NODES) return;
    float4 adv = *(const float4*)(asad1 + n * 8 + 4);
    float ad[4] = {adv.x, adv.y, adv.z, adv.w};
    float4 asv = *(const float4*)(asad1 + n * 8);
    float asl[4] = {asv.x, asv.y, asv.z, asv.w};
    float xs[9];
#pragma unroll
    for (int k = 0; k < 9; k++) xs[k] = x[n * 9 + k];
    float acc[4][9], z[4];
#pragma unroll
    for (int h = 0; h < 4; h++) {
        float e = __expf(lrelu(asl[h] + ad[h]));  // self loop
        z[h] = e;
#pragma unroll
        for (int k = 0; k < 9; k++) acc[h][k] = e * xs[k];
    }
    int dg = deg[n];
    if (dg > CAP) dg = CAP;
    for (int j = 0; j < dg; j++) {
        int s = bucket[n * CAP + j];
        float4 av = *(const float4*)(asad1 + s * 8);
        float as_[4] = {av.x, av.y, av.z, av.w};
        float xv[9];
#pragma unroll
        for (int k = 0; k < 9; k++) xv[k] = x[s * 9 + k];
#pragma unroll
        for (int h = 0; h < 4; h++) {
            float e = __expf(lrelu(as_[h] + ad[h]));
            z[h] += e;
#pragma unroll
            for (int k = 0; k < 9; k++) acc[h][k] += e * xv[k];
        }
    }
#pragma unroll
    for (int h = 0; h < 4; h++) {
        float inv = 1.f / z[h];
#pragma unroll
        for (int k = 0; k < 9; k++) aggN[n * 36 + h * 9 + k] = acc[h][k] * inv;
    }
}

// pre-transpose + bf16-convert W2 [512,128] -> wsB [n=128][k=512]
__global__ void k_packB(const float* __restrict__ W2, __bf16* __restrict__ wsB) {
    int t = blockIdx.x * 256 + threadIdx.x;   // 65536 threads
    int k = t >> 7, n = t & 127;
    wsB[(size_t)n * 512 + k] = (__bf16)W2[(size_t)k * 128 + n];
}

// Fused GEMM, 2-barrier structure:
//   block = 64 rows x 128 cols, 512 threads (8 waves), K=512
//   phase 0: B-regs loaded once from global (overlaps phase 1)
//   phase 1: h2[64][512] = elu(aggN@W1+b1) -> bf16 LDS (1 barrier before+after)
//   phase 2: barrier-free MFMA sweep; wave w owns cols [w*16, w*16+16)
//   epilogue: p2 store + asad2 via LDS cross-wave reduction (no atomics)
#define AS_STRIDE 520
__global__ __launch_bounds__(512, 4) void k_gemm_mfma(
    const float* __restrict__ aggN, const float* __restrict__ W1,
    const float* __restrict__ b1, const __bf16* __restrict__ wsB,
    const float* __restrict__ a_src2, const float* __restrict__ a_dst2,
    float* __restrict__ p2, float* __restrict__ asad2) {
    __shared__ __bf16 As[64 * AS_STRIDE];   // 66560 B
    __shared__ float AgT[64 * 48];          // 12288 B; reused as reduction scratch
    const int tid = threadIdx.x;
    const int lane = tid & 63;
    const int w = tid >> 6;        // wave 0..7
    const int i = lane & 15;       // mfma n/m lane index
    const int q = lane >> 4;       // quad
    const int m0 = blockIdx.x * 64;

    // ---- phase 0: B registers (16 cols per wave, full K) ----
    bf16x8 breg[16];
    {
        const __bf16* bp = wsB + (size_t)(w * 16 + i) * 512 + q * 8;
#pragma unroll
        for (int kc = 0; kc < 16; kc++) breg[kc] = *(const bf16x8*)(bp + kc * 32);
    }

    // ---- stage aggN tile: [row][h*12+k] (16B-aligned head slices) ----
    for (int t = tid; t < 64 * 36; t += 512) {
        int row = t / 36, c = t - row * 36;
        int h = c / 9, k = c - h * 9;
        float v = (m0 + row < N_NODES) ? aggN[(size_t)(m0 + row) * 36 + c] : 0.f;
        AgT[row * 48 + h * 12 + k] = v;
    }
    __syncthreads();

    // ---- phase 1: h2 column tid, 64 rows ----
    {
        int j = tid, h = j >> 7;
        float w1r[9];
#pragma unroll
        for (int k = 0; k < 9; k++) w1r[k] = W1[k * 512 + j];
        float bb = b1[j];
#pragma unroll 2
        for (int r = 0; r < 64; r++) {
            const float* ar = &AgT[r * 48 + h * 12];
            f32x4 a0 = *(const f32x4*)ar;
            f32x4 a1 = *(const f32x4*)(ar + 4);
            float a8 = ar[8];
            float o = bb + a0.x * w1r[0] + a0.y * w1r[1] + a0.z * w1r[2] + a0.w * w1r[3]
                        + a1.x * w1r[4] + a1.y * w1r[5] + a1.z * w1r[6] + a1.w * w1r[7]
                        + a8 * w1r[8];
            As[r * AS_STRIDE + j] = (__bf16)elu(o);
        }
    }
    __syncthreads();

    // ---- phase 2: MFMA sweep (no barriers) ----
    f32x4 acc[4];
#pragma unroll
    for (int r = 0; r < 4; r++) acc[r] = (f32x4){0.f, 0.f, 0.f, 0.f};
#pragma unroll
    for (int kc = 0; kc < 16; kc++) {
#pragma unroll
        for (int r = 0; r < 4; r++) {
            bf16x8 af = *(const bf16x8*)&As[(r * 16 + i) * AS_STRIDE + kc * 32 + q * 8];
            acc[r] = __builtin_amdgcn_mfma_f32_16x16x32_bf16(af, breg[kc], acc[r], 0, 0, 0);
        }
    }

    // ---- epilogue: p2 + asad2 partials ----
    float as2 = a_src2[w * 16 + i];
    float ad2 = a_dst2[w * 16 + i];
    float* red = AgT;  // safe: AgT reads finished before the phase-1 exit barrier
#pragma unroll
    for (int r = 0; r < 4; r++) {
#pragma unroll
        for (int qq = 0; qq < 4; qq++) {
            int row = r * 16 + q * 4 + qq;
            float v = acc[r][qq];
            if (m0 + row < N_NODES)
                p2[(size_t)(m0 + row) * 128 + w * 16 + i] = v;
            float s = v * as2, d = v * ad2;
#pragma unroll
            for (int off = 1; off < 16; off <<= 1) {
                s += __shfl_xor(s, off);
                d += __shfl_xor(d, off);
            }
            if (i == 0) {
                red[row * 16 + w * 2] = s;
                red[row * 16 + w * 2 + 1] = d;
            }
        }
    }
    __syncthreads();
    if (tid < 128) {
        int row = tid >> 1, c = tid & 1;
        float sum = 0.f;
#pragma unroll
        for (int ww = 0; ww < 8; ww++) sum += red[row * 16 + ww * 2 + c];
        if (m0 + row < N_NODES) asad2[(size_t)(m0 + row) * 2 + c] = sum;
    }
}

// layer-2 attention + aggregation + elu + fused graph-sum.
// One wave per 8 consecutive nodes; batch is sorted -> accumulate runs locally,
// flush with atomics only on graph transitions (~6x fewer atomics).
__global__ void k_agg2_pool(const float* __restrict__ p2, const float* __restrict__ asad2,
                            const int* __restrict__ deg, const int* __restrict__ bucket,
                            const float* __restrict__ b2, const int* __restrict__ batch,
                            float* __restrict__ out) {
    int wv = (blockIdx.x * 256 + threadIdx.x) >> 6;
    int lane = threadIdx.x & 63;
    int nbase = wv * 8;
    if (nbase >= N_NODES) return;
    int nend = nbase + 8;
    if (nend > N_NODES) nend = N_NODES;
    float b2a = b2[lane], b2b = b2[64 + lane];
    float g0 = 0.f, g1 = 0.f;
    int curg = batch[nbase];
    for (int n = nbase; n < nend; n++) {
        float ad = asad2[n * 2 + 1];
        float e = __expf(lrelu(asad2[n * 2] + ad));  // self loop
        float z = e;
        float a0 = e * p2[(size_t)n * 128 + lane];
        float a1 = e * p2[(size_t)n * 128 + 64 + lane];
        int dg = deg[n];
        if (dg > CAP) dg = CAP;
        for (int j = 0; j < dg; j++) {
            int s = bucket[n * CAP + j];
            float e2 = __expf(lrelu(asad2[s * 2] + ad));
            z += e2;
            a0 += e2 * p2[(size_t)s * 128 + lane];
            a1 += e2 * p2[(size_t)s * 128 + 64 + lane];
        }
        float inv = 1.f / z;
        float o0 = elu(a0 * inv + b2a);
        float o1 = elu(a1 * inv + b2b);
        int g = batch[n];
        if (g != curg) {
            atomicAdd(&out[(size_t)curg * 128 + lane], g0);
            atomicAdd(&out[(size_t)curg * 128 + 64 + lane], g1);
            g0 = 0.f; g1 = 0.f; curg = g;
        }
        g0 += o0; g1 += o1;
    }
    atomicAdd(&out[(size_t)curg * 128 + lane], g0);
    atomicAdd(&out[(size_t)curg * 128 + 64 + lane], g1);
}

// graph start offsets via binary search (batch is sorted)
__global__ void k_gstart(const int* __restrict__ batch, int* __restrict__ gstart) {
    int g = blockIdx.x * 256 + threadIdx.x;
    if (g > N_GRAPHS) return;
    int lo = 0, hi = N_NODES;
    while (lo < hi) {
        int mid = (lo + hi) >> 1;
        if (batch[mid] < g) lo = mid + 1; else hi = mid;
    }
    gstart[g] = lo;
}

// divide pooled sums by per-graph node counts
__global__ void k_div(const int* __restrict__ gstart, float* __restrict__ out) {
    int g = blockIdx.x, j = threadIdx.x;
    int c = gstart[g + 1] - gstart[g];
    out[(size_t)g * 128 + j] /= (float)(c > 0 ? c : 1);
}

extern "C" void kernel_launch(void* const* d_in, const int* in_sizes, int n_in,
                              void* d_out, int out_size, void* d_ws, size_t ws_size,
                              hipStream_t stream) {
    const float* x       = (const float*)d_in[0];
    const int*   ei      = (const int*)d_in[1];
    const int*   batch   = (const int*)d_in[2];
    const float* W1      = (const float*)d_in[3];
    const float* a_src1  = (const float*)d_in[4];
    const float* a_dst1  = (const float*)d_in[5];
    const float* b1      = (const float*)d_in[6];
    const float* W2      = (const float*)d_in[7];
    const float* a_src2  = (const float*)d_in[8];
    const float* a_dst2  = (const float*)d_in[9];
    const float* b2      = (const float*)d_in[10];
    float* out = (float*)d_out;

    float* wsf   = (float*)d_ws;
    float* asad1 = wsf + OFF_ASAD1;
    float* wf    = wsf + OFF_WF;
    float* aggN  = wsf + OFF_AGGN;
    float* p2    = wsf + OFF_P2;
    float* asad2 = wsf + OFF_ASAD2;
    __bf16* wsB  = (__bf16*)(wsf + OFF_WSB);
    int* wsi    = (int*)(wsf + OFF_INT);
    int* deg    = wsi;
    int* bucket = wsi + N_NODES;
    int* gstart = wsi + N_NODES + (size_t)N_NODES * CAP;

    hipMemsetAsync(deg, 0, N_NODES * sizeof(int), stream);
    hipMemsetAsync(out, 0, (size_t)out_size * sizeof(float), stream);

    k_fold1<<<72, 128, 0, stream>>>(W1, a_src1, a_dst1, wf);
    k_asad1<<<(N_NODES + 255) / 256, 256, 0, stream>>>(x, wf, asad1);
    k_bucket<<<(N_EDGES + 255) / 256, 256, 0, stream>>>(ei, deg, bucket);
    k_agg1<<<(N_NODES + 255) / 256, 256, 0, stream>>>(x, asad1, deg, bucket, aggN);
    k_packB<<<256, 256, 0, stream>>>(W2, wsB);
    k_gemm_mfma<<<(N_NODES + 63) / 64, 512, 0, stream>>>(aggN, W1, b1, wsB,
                                                         a_src2, a_dst2, p2, asad2);
    k_gstart<<<(N_GRAPHS + 256) / 256, 256, 0, stream>>>(batch, gstart);
    k_agg2_pool<<<((N_NODES + 7) / 8 * 64 + 255) / 256, 256, 0, stream>>>(
        p2, asad2, deg, bucket, b2, batch, out);
    k_div<<<N_GRAPHS, 128, 0, stream>>>(gstart, out);
}

// Round 5
// 260.860 us; speedup vs baseline: 1.9461x; 1.0459x over previous
//
#include <hip/hip_runtime.h>

#define N_NODES 100000
#define N_EDGES 300000
#define N_GRAPHS 4000
#define CAP 32

typedef float f32x4 __attribute__((ext_vector_type(4)));
typedef __bf16 bf16x8 __attribute__((ext_vector_type(8)));

// ---------------- workspace layout (float offsets) ----------------
static const size_t OFF_ASAD1 = 0;                                  // N*8
static const size_t OFF_WF    = OFF_ASAD1 + (size_t)N_NODES * 8;    // 128
static const size_t OFF_AGGN  = OFF_WF + 128;                       // N*36
static const size_t OFF_P2    = OFF_AGGN + (size_t)N_NODES * 36;    // N*128
static const size_t OFF_ASAD2 = OFF_P2 + (size_t)N_NODES * 128;     // N*2
static const size_t OFF_WSB   = OFF_ASAD2 + (size_t)N_NODES * 2;    // 32768 floats = 65536 bf16
static const size_t OFF_INT   = OFF_WSB + 32768;                    // deg[N], bucket[N*CAP]

__device__ __forceinline__ float lrelu(float x) { return x < 0.f ? 0.2f * x : x; }
__device__ __forceinline__ float elu(float x)   { return x > 0.f ? x : __expf(x) - 1.f; }

// fold W1 with a_src1/a_dst1 -> wf[isd*36 + k*4 + h]
__global__ void k_fold1(const float* __restrict__ W1, const float* __restrict__ a_src1,
                        const float* __restrict__ a_dst1, float* __restrict__ wf) {
    int o = blockIdx.x;            // 72 blocks
    int c = threadIdx.x;           // 128 threads
    int isd = o / 36, r = o % 36, k = r / 4, h = r % 4;
    const float* a = isd ? a_dst1 : a_src1;
    float v = W1[k * 512 + h * 128 + c] * a[h * 128 + c];
    __shared__ float red[128];
    red[c] = v;
    __syncthreads();
    for (int s = 64; s > 0; s >>= 1) {
        if (c < s) red[c] += red[c + s];
        __syncthreads();
    }
    if (c == 0) wf[isd * 36 + k * 4 + h] = red[0];
}

// per-node attention scalars for layer 1
__global__ void k_asad1(const float* __restrict__ x, const float* __restrict__ wf,
                        float* __restrict__ asad1) {
    int n = blockIdx.x * 256 + threadIdx.x;
    if (n >= N_NODES) return;
    float xv[9];
#pragma unroll
    for (int k = 0; k < 9; k++) xv[k] = x[n * 9 + k];
#pragma unroll
    for (int h = 0; h < 4; h++) {
        float s = 0.f, d = 0.f;
#pragma unroll
        for (int k = 0; k < 9; k++) {
            s += xv[k] * wf[k * 4 + h];
            d += xv[k] * wf[36 + k * 4 + h];
        }
        asad1[n * 8 + h] = s;
        asad1[n * 8 + 4 + h] = d;
    }
}

// build per-dst bucket of src ids
__global__ void k_bucket(const int* __restrict__ ei, int* __restrict__ deg,
                         int* __restrict__ bucket) {
    int e = blockIdx.x * 256 + threadIdx.x;
    if (e >= N_EDGES) return;
    int s = ei[e], d = ei[N_EDGES + e];
    int slot = atomicAdd(&deg[d], 1);
    if (slot < CAP) bucket[d * CAP + slot] = s;
}

// layer-1 attention + aggregation of x (normalized)
__global__ void k_agg1(const float* __restrict__ x, const float* __restrict__ asad1,
                       const int* __restrict__ deg, const int* __restrict__ bucket,
                       float* __restrict__ aggN) {
    int n = blockIdx.x * 256 + threadIdx.x;
    if (n >= N_NODES) return;
    float4 adv = *(const float4*)(asad1 + n * 8 + 4);
    float ad[4] = {adv.x, adv.y, adv.z, adv.w};
    float4 asv = *(const float4*)(asad1 + n * 8);
    float asl[4] = {asv.x, asv.y, asv.z, asv.w};
    float xs[9];
#pragma unroll
    for (int k = 0; k < 9; k++) xs[k] = x[n * 9 + k];
    float acc[4][9], z[4];
#pragma unroll
    for (int h = 0; h < 4; h++) {
        float e = __expf(lrelu(asl[h] + ad[h]));  // self loop
        z[h] = e;
#pragma unroll
        for (int k = 0; k < 9; k++) acc[h][k] = e * xs[k];
    }
    int dg = deg[n];
    if (dg > CAP) dg = CAP;
    for (int j = 0; j < dg; j++) {
        int s = bucket[n * CAP + j];
        float4 av = *(const float4*)(asad1 + s * 8);
        float as_[4] = {av.x, av.y, av.z, av.w};
        float xv[9];
#pragma unroll
        for (int k = 0; k < 9; k++) xv[k] = x[s * 9 + k];
#pragma unroll
        for (int h = 0; h < 4; h++) {
            float e = __expf(lrelu(as_[h] + ad[h]));
            z[h] += e;
#pragma unroll
            for (int k = 0; k < 9; k++) acc[h][k] += e * xv[k];
        }
    }
#pragma unroll
    for (int h = 0; h < 4; h++) {
        float inv = 1.f / z[h];
#pragma unroll
        for (int k = 0; k < 9; k++) aggN[n * 36 + h * 9 + k] = acc[h][k] * inv;
    }
}

// pre-transpose + bf16-convert W2 [512,128] -> wsB [n=128][k=512]
__global__ void k_packB(const float* __restrict__ W2, __bf16* __restrict__ wsB) {
    int t = blockIdx.x * 256 + threadIdx.x;   // 65536 threads
    int k = t >> 7, n = t & 127;
    wsB[(size_t)n * 512 + k] = (__bf16)W2[(size_t)k * 128 + n];
}

// Fused GEMM, frag-major LDS:
//   block = 64 rows x 128 cols, 512 threads (8 waves), K=512
//   As = 64 A-fragment tiles (tile t = rt*16+kc, 1 KB each, lane l at t*1024+l*16)
//   phase 1: thread (row, kgroup) computes h2 for 64 cols -> 8 bf16x8 frag writes
//   phase 2: wave (wy in 2, wx in 4) = 32 rows x 32 cols; A-frags from LDS
//            (conflict-free lane-contiguous), B-frags streamed from L2-hot wsB
//   epilogue: p2 store + asad2 via LDS cross-wave reduction
__global__ __launch_bounds__(512, 2) void k_gemm_mfma(
    const float* __restrict__ aggN, const float* __restrict__ W1,
    const float* __restrict__ b1, const __bf16* __restrict__ wsB,
    const float* __restrict__ a_src2, const float* __restrict__ a_dst2,
    float* __restrict__ p2, float* __restrict__ asad2) {
    __shared__ __bf16 As[64 * 512];   // 64 KB, frag-major
    __shared__ float AgT[64 * 48];    // 12 KB; reused as reduction scratch
    const int tid = threadIdx.x;
    const int lane = tid & 63;
    const int w = tid >> 6;
    const int i = lane & 15;
    const int q = lane >> 4;
    const int m0 = blockIdx.x * 64;

    // ---- stage aggN tile: [row][h*12+k] ----
    for (int t = tid; t < 64 * 36; t += 512) {
        int row = t / 36, c = t - row * 36;
        int h = c / 9, k = c - h * 9;
        float v = (m0 + row < N_NODES) ? aggN[(size_t)(m0 + row) * 36 + c] : 0.f;
        AgT[row * 48 + h * 12 + k] = v;
    }
    __syncthreads();

    // ---- phase 1: thread = (row = tid&63, kgroup = tid>>6); 64 cols each ----
    {
        int row = tid & 63;
        int kg = __builtin_amdgcn_readfirstlane(tid >> 6);  // wave-uniform -> scalar W1 loads
        int h = kg >> 1;
        const float* ar = &AgT[row * 48 + h * 12];
        float ag[9];
#pragma unroll
        for (int k = 0; k < 9; k++) ag[k] = ar[k];
        int rt = row >> 4, il = row & 15;
#pragma unroll
        for (int c8 = 0; c8 < 8; c8++) {
            int j0 = kg * 64 + c8 * 8;
            float o[8];
#pragma unroll
            for (int e = 0; e < 8; e++) o[e] = b1[j0 + e];
#pragma unroll
            for (int k = 0; k < 9; k++) {
                const float* wp = &W1[k * 512 + j0];
#pragma unroll
                for (int e = 0; e < 8; e++) o[e] += ag[k] * wp[e];
            }
            bf16x8 pk;
#pragma unroll
            for (int e = 0; e < 8; e++) pk[e] = (__bf16)elu(o[e]);
            int tile = rt * 16 + (kg * 2 + (c8 >> 2));
            *(bf16x8*)&As[tile * 512 + ((c8 & 3) * 16 + il) * 8] = pk;
        }
    }
    __syncthreads();

    // ---- phase 2: MFMA sweep, no barriers ----
    const int wy = w >> 2, wx = w & 3;
    f32x4 acc[2][2];
#pragma unroll
    for (int r = 0; r < 2; r++)
#pragma unroll
        for (int c = 0; c < 2; c++) acc[r][c] = (f32x4){0.f, 0.f, 0.f, 0.f};
#pragma unroll
    for (int kc = 0; kc < 16; kc++) {
        bf16x8 bfr[2], af[2];
#pragma unroll
        for (int c = 0; c < 2; c++)
            bfr[c] = *(const bf16x8*)&wsB[(size_t)(wx * 32 + c * 16 + i) * 512 + kc * 32 + q * 8];
#pragma unroll
        for (int r = 0; r < 2; r++)
            af[r] = *(const bf16x8*)&As[((wy * 2 + r) * 16 + kc) * 512 + lane * 8];
#pragma unroll
        for (int r = 0; r < 2; r++)
#pragma unroll
            for (int c = 0; c < 2; c++)
                acc[r][c] = __builtin_amdgcn_mfma_f32_16x16x32_bf16(af[r], bfr[c], acc[r][c], 0, 0, 0);
    }

    // ---- epilogue: p2 + asad2 partials ----
    float as2[2], ad2[2];
#pragma unroll
    for (int c = 0; c < 2; c++) {
        int col = wx * 32 + c * 16 + i;
        as2[c] = a_src2[col];
        ad2[c] = a_dst2[col];
    }
    float* red = AgT;  // safe: all AgT reads were before the phase-1 exit barrier
#pragma unroll
    for (int r = 0; r < 2; r++) {
#pragma unroll
        for (int qq = 0; qq < 4; qq++) {
            int row = wy * 32 + r * 16 + q * 4 + qq;
            float s = 0.f, d = 0.f;
#pragma unroll
            for (int c = 0; c < 2; c++) {
                float v = acc[r][c][qq];
                s += v * as2[c];
                d += v * ad2[c];
                if (m0 + row < N_NODES)
                    p2[(size_t)(m0 + row) * 128 + wx * 32 + c * 16 + i] = v;
            }
#pragma unroll
            for (int off = 1; off < 16; off <<= 1) {
                s += __shfl_xor(s, off);
                d += __shfl_xor(d, off);
            }
            if (i == 0) {
                red[row * 8 + wx * 2] = s;
                red[row * 8 + wx * 2 + 1] = d;
            }
        }
    }
    __syncthreads();
    if (tid < 128) {
        int row = tid >> 1, cc = tid & 1;
        float sum = red[row * 8 + cc] + red[row * 8 + 2 + cc]
                  + red[row * 8 + 4 + cc] + red[row * 8 + 6 + cc];
        if (m0 + row < N_NODES) asad2[(size_t)(m0 + row) * 2 + cc] = sum;
    }
}

// layer-2 attention + aggregation + elu + fused graph-sum.
// One wave per 8 consecutive nodes; batch is sorted -> accumulate runs locally,
// flush with atomics only on graph transitions.
__global__ void k_agg2_pool(const float* __restrict__ p2, const float* __restrict__ asad2,
                            const int* __restrict__ deg, const int* __restrict__ bucket,
                            const float* __restrict__ b2, const int* __restrict__ batch,
                            float* __restrict__ out) {
    int wv = (blockIdx.x * 256 + threadIdx.x) >> 6;
    int lane = threadIdx.x & 63;
    int nbase = wv * 8;
    if (nbase >= N_NODES) return;
    int nend = nbase + 8;
    if (nend > N_NODES) nend = N_NODES;
    float b2a = b2[lane], b2b = b2[64 + lane];
    float g0 = 0.f, g1 = 0.f;
    int curg = batch[nbase];
    for (int n = nbase; n < nend; n++) {
        float ad = asad2[n * 2 + 1];
        float e = __expf(lrelu(asad2[n * 2] + ad));  // self loop
        float z = e;
        float a0 = e * p2[(size_t)n * 128 + lane];
        float a1 = e * p2[(size_t)n * 128 + 64 + lane];
        int dg = deg[n];
        if (dg > CAP) dg = CAP;
        for (int j = 0; j < dg; j++) {
            int s = bucket[n * CAP + j];
            float e2 = __expf(lrelu(asad2[s * 2] + ad));
            z += e2;
            a0 += e2 * p2[(size_t)s * 128 + lane];
            a1 += e2 * p2[(size_t)s * 128 + 64 + lane];
        }
        float inv = 1.f / z;
        float o0 = elu(a0 * inv + b2a);
        float o1 = elu(a1 * inv + b2b);
        int g = batch[n];
        if (g != curg) {
            atomicAdd(&out[(size_t)curg * 128 + lane], g0);
            atomicAdd(&out[(size_t)curg * 128 + 64 + lane], g1);
            g0 = 0.f; g1 = 0.f; curg = g;
        }
        g0 += o0; g1 += o1;
    }
    atomicAdd(&out[(size_t)curg * 128 + lane], g0);
    atomicAdd(&out[(size_t)curg * 128 + 64 + lane], g1);
}

// divide pooled sums by per-graph node counts (binary search inline; batch sorted)
__global__ void k_div(const int* __restrict__ batch, float* __restrict__ out) {
    int g = blockIdx.x, j = threadIdx.x;
    int lo = 0, hi = N_NODES;
    while (lo < hi) {
        int mid = (lo + hi) >> 1;
        if (batch[mid] < g) lo = mid + 1; else hi = mid;
    }
    int s = lo;
    hi = N_NODES;
    while (lo < hi) {
        int mid = (lo + hi) >> 1;
        if (batch[mid] < g + 1) lo = mid + 1; else hi = mid;
    }
    int c = lo - s;
    out[(size_t)g * 128 + j] /= (float)(c > 0 ? c : 1);
}

extern "C" void kernel_launch(void* const* d_in, const int* in_sizes, int n_in,
                              void* d_out, int out_size, void* d_ws, size_t ws_size,
                              hipStream_t stream) {
    const float* x       = (const float*)d_in[0];
    const int*   ei      = (const int*)d_in[1];
    const int*   batch   = (const int*)d_in[2];
    const float* W1      = (const float*)d_in[3];
    const float* a_src1  = (const float*)d_in[4];
    const float* a_dst1  = (const float*)d_in[5];
    const float* b1      = (const float*)d_in[6];
    const float* W2      = (const float*)d_in[7];
    const float* a_src2  = (const float*)d_in[8];
    const float* a_dst2  = (const float*)d_in[9];
    const float* b2      = (const float*)d_in[10];
    float* out = (float*)d_out;

    float* wsf   = (float*)d_ws;
    float* asad1 = wsf + OFF_ASAD1;
    float* wf    = wsf + OFF_WF;
    float* aggN  = wsf + OFF_AGGN;
    float* p2    = wsf + OFF_P2;
    float* asad2 = wsf + OFF_ASAD2;
    __bf16* wsB  = (__bf16*)(wsf + OFF_WSB);
    int* wsi    = (int*)(wsf + OFF_INT);
    int* deg    = wsi;
    int* bucket = wsi + N_NODES;

    hipMemsetAsync(deg, 0, N_NODES * sizeof(int), stream);
    hipMemsetAsync(out, 0, (size_t)out_size * sizeof(float), stream);

    k_fold1<<<72, 128, 0, stream>>>(W1, a_src1, a_dst1, wf);
    k_asad1<<<(N_NODES + 255) / 256, 256, 0, stream>>>(x, wf, asad1);
    k_bucket<<<(N_EDGES + 255) / 256, 256, 0, stream>>>(ei, deg, bucket);
    k_agg1<<<(N_NODES + 255) / 256, 256, 0, stream>>>(x, asad1, deg, bucket, aggN);
    k_packB<<<256, 256, 0, stream>>>(W2, wsB);
    k_gemm_mfma<<<(N_NODES + 63) / 64, 512, 0, stream>>>(aggN, W1, b1, wsB,
                                                         a_src2, a_dst2, p2, asad2);
    k_agg2_pool<<<((N_NODES + 7) / 8 * 64 + 255) / 256, 256, 0, stream>>>(
        p2, asad2, deg, bucket, b2, batch, out);
    k_div<<<N_GRAPHS, 128, 0, stream>>>(batch, out);
}

// Round 7
// 255.568 us; speedup vs baseline: 1.9864x; 1.0207x over previous
//
#include <hip/hip_runtime.h>

#define N_NODES 100000
#define N_EDGES 300000
#define N_GRAPHS 4000
#define CAP 32

typedef float f32x4 __attribute__((ext_vector_type(4)));
typedef __bf16 bf16x8 __attribute__((ext_vector_type(8)));
typedef __bf16 bf16x2 __attribute__((ext_vector_type(2)));

// ---------------- workspace layout (float offsets) ----------------
static const size_t OFF_XA    = 0;                                   // N*16: x[9],as1[4],pad[3] (one 64B line)
static const size_t OFF_AD4   = OFF_XA + (size_t)N_NODES * 16;       // N*4
static const size_t OFF_P2B   = OFF_AD4 + (size_t)N_NODES * 4;       // N*128 bf16 = N*64 floats
static const size_t OFF_ASAD2 = OFF_P2B + (size_t)N_NODES * 64;      // N*2
static const size_t OFF_WSB   = OFF_ASAD2 + (size_t)N_NODES * 2;     // 65536 bf16 = 32768 floats
static const size_t OFF_INT   = OFF_WSB + 32768;                     // deg[N], bucket[N*CAP]

// k_pre block partition (256 threads each)
#define PRE_NODE_END 391   // ceil(100000/256) node-pack blocks
#define PRE_PACKB_END 455  // +64 blocks: 16384 threads x 4 = 65536 W2 elements
#define PRE_DEG_END 846    // +391 blocks: zero deg[100000]
#define PRE_OUT_END 1346   // +500 blocks: zero out (128000 float4)

__device__ __forceinline__ float lrelu(float x) { return x < 0.f ? 0.2f * x : x; }
__device__ __forceinline__ float elu(float x)   { return x > 0.f ? x : __expf(x) - 1.f; }

// Fat pre-kernel: node pack (wf fold + xa/ad4) || W2 pack || deg zero || out zero
__global__ __launch_bounds__(256) void k_pre(
    const float* __restrict__ x, const float* __restrict__ W1,
    const float* __restrict__ a_src1, const float* __restrict__ a_dst1,
    const float* __restrict__ W2, float* __restrict__ xa, float* __restrict__ ad4,
    __bf16* __restrict__ wsB, int* __restrict__ deg, float* __restrict__ out) {
    int b = blockIdx.x, tid = threadIdx.x;
    if (b < PRE_NODE_END) {
        __shared__ float wf[72];
        if (tid < 72) {
            int isd = tid / 36, r = tid % 36, k = r / 4, h = r % 4;
            const float* a = isd ? a_dst1 : a_src1;
            float s = 0.f;
            for (int c = 0; c < 128; c++) s += W1[k * 512 + h * 128 + c] * a[h * 128 + c];
            wf[tid] = s;
        }
        __syncthreads();
        int n = b * 256 + tid;
        if (n >= N_NODES) return;
        float xv[9];
#pragma unroll
        for (int k = 0; k < 9; k++) xv[k] = x[n * 9 + k];
        float as[4], ad[4];
#pragma unroll
        for (int h = 0; h < 4; h++) {
            float s = 0.f, d = 0.f;
#pragma unroll
            for (int k = 0; k < 9; k++) {
                s += xv[k] * wf[k * 4 + h];
                d += xv[k] * wf[36 + k * 4 + h];
            }
            as[h] = s; ad[h] = d;
        }
        f32x4* xp = (f32x4*)(xa + (size_t)n * 16);
        xp[0] = (f32x4){xv[0], xv[1], xv[2], xv[3]};
        xp[1] = (f32x4){xv[4], xv[5], xv[6], xv[7]};
        xp[2] = (f32x4){xv[8], as[0], as[1], as[2]};
        xp[3] = (f32x4){as[3], 0.f, 0.f, 0.f};
        *(f32x4*)(ad4 + (size_t)n * 4) = (f32x4){ad[0], ad[1], ad[2], ad[3]};
    } else if (b < PRE_PACKB_END) {
        int t = (b - PRE_NODE_END) * 256 + tid;
#pragma unroll
        for (int m = 0; m < 4; m++) {
            int idx = t * 4 + m;                 // 0..65535
            int k = idx >> 7, nn = idx & 127;
            wsB[(size_t)nn * 512 + k] = (__bf16)W2[(size_t)k * 128 + nn];
        }
    } else if (b < PRE_DEG_END) {
        int idx = (b - PRE_PACKB_END) * 256 + tid;
        if (idx < N_NODES) deg[idx] = 0;
    } else {
        int idx = (b - PRE_DEG_END) * 256 + tid;  // < 128000 float4s
        if (idx < 128000) ((f32x4*)out)[idx] = (f32x4){0.f, 0.f, 0.f, 0.f};
    }
}

// build per-dst bucket of src ids
__global__ void k_bucket(const int* __restrict__ ei, int* __restrict__ deg,
                         int* __restrict__ bucket) {
    int e = blockIdx.x * 256 + threadIdx.x;
    if (e >= N_EDGES) return;
    int s = ei[e], d = ei[N_EDGES + e];
    int slot = atomicAdd(&deg[d], 1);
    if (slot < CAP) bucket[d * CAP + slot] = s;
}

// Mega-kernel: phase 0 = layer-1 attention aggregation (8 threads/node, xa gather);
// phase 1 = h2 = elu(agg@W1+b1) -> bf16 frag-major LDS; phase 2 = MFMA vs wsB
// (prefetch depth 2); epilogue = p2(bf16) store + asad2 cross-wave reduction.
__global__ __launch_bounds__(512, 4) void k_gemm_mfma(
    const float* __restrict__ xa, const float* __restrict__ ad4,
    const int* __restrict__ deg, const int* __restrict__ bucket,
    const float* __restrict__ W1, const float* __restrict__ b1,
    const __bf16* __restrict__ wsB,
    const float* __restrict__ a_src2, const float* __restrict__ a_dst2,
    __bf16* __restrict__ p2b, float* __restrict__ asad2) {
    __shared__ __bf16 As[64 * 512];   // 64 KB frag-major
    __shared__ float AgT[64 * 52];    // 13.3 KB (stride 52: bank-rotating); reused as red scratch
    const int tid = threadIdx.x;
    const int lane = tid & 63;
    const int w = tid >> 6;
    const int i = lane & 15;
    const int q = lane >> 4;
    const int m0 = blockIdx.x * 64;

    // ---- phase 0: fused layer-1 aggregation, 8 threads per node ----
    {
        int r = tid >> 3, s = tid & 7;
        int r0 = m0 + r;
        float acc[4][9] = {};
        float z[4] = {0.f, 0.f, 0.f, 0.f};
        if (r0 < N_NODES) {
            f32x4 adv = *(const f32x4*)(ad4 + (size_t)r0 * 4);
            float ad[4] = {adv.x, adv.y, adv.z, adv.w};
            int dg = deg[r0];
            if (dg > CAP) dg = CAP;
            if (s == 0) {
                const f32x4* xp = (const f32x4*)(xa + (size_t)r0 * 16);
                f32x4 v0 = xp[0], v1 = xp[1], v2 = xp[2], v3 = xp[3];
                float xs[9] = {v0.x, v0.y, v0.z, v0.w, v1.x, v1.y, v1.z, v1.w, v2.x};
                float asl[4] = {v2.y, v2.z, v2.w, v3.x};
#pragma unroll
                for (int h = 0; h < 4; h++) {
                    float e = __expf(lrelu(asl[h] + ad[h]));
                    z[h] += e;
#pragma unroll
                    for (int k = 0; k < 9; k++) acc[h][k] += e * xs[k];
                }
            } else {
                for (int j = s - 1; j < dg; j += 7) {
                    int src = bucket[r0 * CAP + j];
                    const f32x4* xp = (const f32x4*)(xa + (size_t)src * 16);
                    f32x4 v0 = xp[0], v1 = xp[1], v2 = xp[2], v3 = xp[3];
                    float xs[9] = {v0.x, v0.y, v0.z, v0.w, v1.x, v1.y, v1.z, v1.w, v2.x};
                    float asl[4] = {v2.y, v2.z, v2.w, v3.x};
#pragma unroll
                    for (int h = 0; h < 4; h++) {
                        float e = __expf(lrelu(asl[h] + ad[h]));
                        z[h] += e;
#pragma unroll
                        for (int k = 0; k < 9; k++) acc[h][k] += e * xs[k];
                    }
                }
            }
        }
#pragma unroll
        for (int off = 1; off < 8; off <<= 1) {
#pragma unroll
            for (int h = 0; h < 4; h++) {
                z[h] += __shfl_xor(z[h], off);
#pragma unroll
                for (int k = 0; k < 9; k++) acc[h][k] += __shfl_xor(acc[h][k], off);
            }
        }
        if (s == 0) {
#pragma unroll
            for (int h = 0; h < 4; h++) {
                float inv = (r0 < N_NODES) ? 1.f / z[h] : 0.f;
#pragma unroll
                for (int k = 0; k < 9; k++) AgT[r * 52 + h * 12 + k] = acc[h][k] * inv;
            }
        }
    }
    __syncthreads();

    // ---- phase 1: h2 -> bf16 frag-major LDS. thread = (row=tid&63, kgroup=tid>>6) ----
    {
        int row = tid & 63;
        int kg = __builtin_amdgcn_readfirstlane(tid >> 6);  // wave-uniform
        int h = kg >> 1;
        const float* ar = &AgT[row * 52 + h * 12];
        float ag[9];
#pragma unroll
        for (int k = 0; k < 9; k++) ag[k] = ar[k];
        int rt = row >> 4, il = row & 15;
#pragma unroll
        for (int c8 = 0; c8 < 8; c8++) {
            int j0 = kg * 64 + c8 * 8;
            float o[8];
#pragma unroll
            for (int e = 0; e < 8; e++) o[e] = b1[j0 + e];
#pragma unroll
            for (int k = 0; k < 9; k++) {
                const float* wp = &W1[k * 512 + j0];
#pragma unroll
                for (int e = 0; e < 8; e++) o[e] += ag[k] * wp[e];
            }
            bf16x8 pk;
#pragma unroll
            for (int e = 0; e < 8; e++) pk[e] = (__bf16)elu(o[e]);
            int tile = rt * 16 + (kg * 2 + (c8 >> 2));
            *(bf16x8*)&As[tile * 512 + ((c8 & 3) * 16 + il) * 8] = pk;
        }
    }
    __syncthreads();

    // ---- phase 2: MFMA sweep, B prefetch depth 2, no barriers ----
    const int wy = w >> 2, wx = w & 3;
    const __bf16* bbase = wsB + (size_t)(wx * 32 + i) * 512 + q * 8;
#define LOADB(kc, c) (*(const bf16x8*)(bbase + (size_t)(c) * 16 * 512 + (kc) * 32))
    f32x4 acc[2][2];
#pragma unroll
    for (int r = 0; r < 2; r++)
#pragma unroll
        for (int c = 0; c < 2; c++) acc[r][c] = (f32x4){0.f, 0.f, 0.f, 0.f};
    bf16x8 cur0 = LOADB(0, 0), cur1 = LOADB(0, 1);
    bf16x8 nx0 = LOADB(1, 0), nx1 = LOADB(1, 1);
#pragma unroll
    for (int kc = 0; kc < 16; kc++) {
        bf16x8 f0, f1;
        if (kc < 14) { f0 = LOADB(kc + 2, 0); f1 = LOADB(kc + 2, 1); }
        bf16x8 af0 = *(const bf16x8*)&As[((wy * 2 + 0) * 16 + kc) * 512 + lane * 8];
        bf16x8 af1 = *(const bf16x8*)&As[((wy * 2 + 1) * 16 + kc) * 512 + lane * 8];
        acc[0][0] = __builtin_amdgcn_mfma_f32_16x16x32_bf16(af0, cur0, acc[0][0], 0, 0, 0);
        acc[0][1] = __builtin_amdgcn_mfma_f32_16x16x32_bf16(af0, cur1, acc[0][1], 0, 0, 0);
        acc[1][0] = __builtin_amdgcn_mfma_f32_16x16x32_bf16(af1, cur0, acc[1][0], 0, 0, 0);
        acc[1][1] = __builtin_amdgcn_mfma_f32_16x16x32_bf16(af1, cur1, acc[1][1], 0, 0, 0);
        cur0 = nx0; cur1 = nx1; nx0 = f0; nx1 = f1;
    }
#undef LOADB

    // ---- epilogue: p2 (bf16) + asad2 via LDS cross-wave reduction ----
    float as2[2], ad2[2];
#pragma unroll
    for (int c = 0; c < 2; c++) {
        int col = wx * 32 + c * 16 + i;
        as2[c] = a_src2[col];
        ad2[c] = a_dst2[col];
    }
    float* red = AgT;
#pragma unroll
    for (int r = 0; r < 2; r++) {
#pragma unroll
        for (int qq = 0; qq < 4; qq++) {
            int row = wy * 32 + r * 16 + q * 4 + qq;
            float s = 0.f, d = 0.f;
#pragma unroll
            for (int c = 0; c < 2; c++) {
                float v = acc[r][c][qq];
                s += v * as2[c];
                d += v * ad2[c];
                if (m0 + row < N_NODES)
                    p2b[(size_t)(m0 + row) * 128 + wx * 32 + c * 16 + i] = (__bf16)v;
            }
#pragma unroll
            for (int off = 1; off < 16; off <<= 1) {
                s += __shfl_xor(s, off);
                d += __shfl_xor(d, off);
            }
            if (i == 0) {
                red[row * 8 + wx * 2] = s;
                red[row * 8 + wx * 2 + 1] = d;
            }
        }
    }
    __syncthreads();
    if (tid < 128) {
        int row = tid >> 1, cc = tid & 1;
        float sum = red[row * 8 + cc] + red[row * 8 + 2 + cc]
                  + red[row * 8 + 4 + cc] + red[row * 8 + 6 + cc];
        if (m0 + row < N_NODES) asad2[(size_t)(m0 + row) * 2 + cc] = sum;
    }
}

// layer-2 attention + aggregation + elu + fused graph-sum (bf16 p2, lane owns col pair).
__global__ void k_agg2_pool(const __bf16* __restrict__ p2b, const float* __restrict__ asad2,
                            const int* __restrict__ deg, const int* __restrict__ bucket,
                            const float* __restrict__ b2, const int* __restrict__ batch,
                            float* __restrict__ out) {
    int wv = (blockIdx.x * 256 + threadIdx.x) >> 6;
    int lane = threadIdx.x & 63;
    int nbase = wv * 8;
    if (nbase >= N_NODES) return;
    int nend = nbase + 8;
    if (nend > N_NODES) nend = N_NODES;
    float b2a = b2[2 * lane], b2b = b2[2 * lane + 1];
    float g0 = 0.f, g1 = 0.f;
    int curg = batch[nbase];
    for (int n = nbase; n < nend; n++) {
        float ad = asad2[n * 2 + 1];
        float e = __expf(lrelu(asad2[n * 2] + ad));  // self loop
        float z = e;
        bf16x2 v = ((const bf16x2*)(p2b + (size_t)n * 128))[lane];
        float a0 = e * (float)v.x;
        float a1 = e * (float)v.y;
        int dg = deg[n];
        if (dg > CAP) dg = CAP;
        for (int j = 0; j < dg; j++) {
            int s = bucket[n * CAP + j];
            float e2 = __expf(lrelu(asad2[s * 2] + ad));
            z += e2;
            bf16x2 sv = ((const bf16x2*)(p2b + (size_t)s * 128))[lane];
            a0 += e2 * (float)sv.x;
            a1 += e2 * (float)sv.y;
        }
        float inv = 1.f / z;
        float o0 = elu(a0 * inv + b2a);
        float o1 = elu(a1 * inv + b2b);
        int g = batch[n];
        if (g != curg) {
            atomicAdd(&out[(size_t)curg * 128 + 2 * lane], g0);
            atomicAdd(&out[(size_t)curg * 128 + 2 * lane + 1], g1);
            g0 = 0.f; g1 = 0.f; curg = g;
        }
        g0 += o0; g1 += o1;
    }
    atomicAdd(&out[(size_t)curg * 128 + 2 * lane], g0);
    atomicAdd(&out[(size_t)curg * 128 + 2 * lane + 1], g1);
}

// divide pooled sums by per-graph node counts (binary search; batch sorted)
__global__ void k_div(const int* __restrict__ batch, float* __restrict__ out) {
    int g = blockIdx.x, j = threadIdx.x;
    int lo = 0, hi = N_NODES;
    while (lo < hi) {
        int mid = (lo + hi) >> 1;
        if (batch[mid] < g) lo = mid + 1; else hi = mid;
    }
    int s = lo;
    hi = N_NODES;
    while (lo < hi) {
        int mid = (lo + hi) >> 1;
        if (batch[mid] < g + 1) lo = mid + 1; else hi = mid;
    }
    int c = lo - s;
    out[(size_t)g * 128 + j] /= (float)(c > 0 ? c : 1);
}

extern "C" void kernel_launch(void* const* d_in, const int* in_sizes, int n_in,
                              void* d_out, int out_size, void* d_ws, size_t ws_size,
                              hipStream_t stream) {
    const float* x       = (const float*)d_in[0];
    const int*   ei      = (const int*)d_in[1];
    const int*   batch   = (const int*)d_in[2];
    const float* W1      = (const float*)d_in[3];
    const float* a_src1  = (const float*)d_in[4];
    const float* a_dst1  = (const float*)d_in[5];
    const float* b1      = (const float*)d_in[6];
    const float* W2      = (const float*)d_in[7];
    const float* a_src2  = (const float*)d_in[8];
    const float* a_dst2  = (const float*)d_in[9];
    const float* b2      = (const float*)d_in[10];
    float* out = (float*)d_out;

    float* wsf   = (float*)d_ws;
    float* xa    = wsf + OFF_XA;
    float* ad4   = wsf + OFF_AD4;
    __bf16* p2b  = (__bf16*)(wsf + OFF_P2B);
    float* asad2 = wsf + OFF_ASAD2;
    __bf16* wsB  = (__bf16*)(wsf + OFF_WSB);
    int* wsi    = (int*)(wsf + OFF_INT);
    int* deg    = wsi;
    int* bucket = wsi + N_NODES;

    k_pre<<<PRE_OUT_END, 256, 0, stream>>>(x, W1, a_src1, a_dst1, W2, xa, ad4, wsB, deg, out);
    k_bucket<<<(N_EDGES + 255) / 256, 256, 0, stream>>>(ei, deg, bucket);
    k_gemm_mfma<<<(N_NODES + 63) / 64, 512, 0, stream>>>(xa, ad4, deg, bucket, W1, b1,
                                                         wsB, a_src2, a_dst2, p2b, asad2);
    k_agg2_pool<<<((N_NODES + 7) / 8 * 64 + 255) / 256, 256, 0, stream>>>(
        p2b, asad2, deg, bucket, b2, batch, out);
    k_div<<<N_GRAPHS, 128, 0, stream>>>(batch, out);
}